// Round 13
// baseline (554.017 us; speedup 1.0000x reference)
//
#include <hip/hip_runtime.h>
#include <math.h>

#define DM 3136
#define DH 512

// physical LDS index for transposed [k][m] tiles with bank swizzle:
// bank(k*64+m) = m%32 -> 4-way conflict on kb groups; XOR bit4 of m with bit4
// of k makes kb in {0,16,32,48} map to 2 bank classes (2-way = free, m136).
#define SWZ(k, m) (((k) * 64) + ((m) ^ ((k) & 16)))

#define MICRO_4x4 \
    acc[0][0] += a.x*b.x; acc[0][1] += a.x*b.y; acc[0][2] += a.x*b.z; acc[0][3] += a.x*b.w; \
    acc[1][0] += a.y*b.x; acc[1][1] += a.y*b.y; acc[1][2] += a.y*b.z; acc[1][3] += a.y*b.w; \
    acc[2][0] += a.z*b.x; acc[2][1] += a.z*b.y; acc[2][2] += a.z*b.z; acc[2][3] += a.z*b.w; \
    acc[3][0] += a.w*b.x; acc[3][1] += a.w*b.y; acc[3][2] += a.w*b.z; acc[3][3] += a.w*b.w;

// ---------------- gelu ----------------
__device__ __forceinline__ void gelu_both(float xx, float& g, float& gp) {
  const float c = 0.7978845608028654f;
  const float a = 0.044715f;
  float x2 = xx * xx;
  float u = c * (xx + a * xx * x2);
  float t = tanhf(u);
  g  = 0.5f * xx * (1.f + t);
  gp = 0.5f * (1.f + t) + 0.5f * xx * (1.f - t * t) * c * (1.f + 3.f * a * x2);
}
__device__ __forceinline__ float gelu_only(float xx) {
  const float c = 0.7978845608028654f;
  const float a = 0.044715f;
  float u = c * (xx + a * xx * xx * xx);
  return 0.5f * xx * (1.f + tanhf(u));
}

// ---------------- conv3x3 + RMSNorm (proven R2) ----------------
__global__ __launch_bounds__(256) void conv_rms(
    const float* __restrict__ x,
    const float* __restrict__ wk, const float* __restrict__ bk,
    const float* __restrict__ wv, const float* __restrict__ bv,
    const float* __restrict__ sk, const float* __restrict__ sv,
    float* __restrict__ nk, float* __restrict__ nv) {
  __shared__ float swk[144], swv[144], sb[16];
  int tid = threadIdx.x;
  if (tid < 144) { swk[tid] = wk[tid]; swv[tid] = wv[tid]; }
  if (tid < 4) {
    sb[tid] = bk[tid]; sb[4 + tid] = bv[tid];
    sb[8 + tid] = sk[tid]; sb[12 + tid] = sv[tid];
  }
  __syncthreads();
  int idx = blockIdx.x * 256 + tid;
  int t = idx / 784, hw = idx - t * 784;
  int h = hw / 28, w = hw - h * 28;
  float ak[4], av[4];
  #pragma unroll
  for (int c = 0; c < 4; ++c) { ak[c] = sb[c]; av[c] = sb[4 + c]; }
  const float* xt = x + (size_t)t * DM;
  for (int kh = 0; kh < 3; ++kh) {
    int ih = h + kh - 1;
    if (ih < 0 || ih >= 28) continue;
    for (int kw = 0; kw < 3; ++kw) {
      int iw = w + kw - 1;
      if (iw < 0 || iw >= 28) continue;
      int base = (kh * 3 + kw) * 16;
      #pragma unroll
      for (int ci = 0; ci < 4; ++ci) {
        float xv = xt[ci * 784 + ih * 28 + iw];
        #pragma unroll
        for (int co = 0; co < 4; ++co) {
          ak[co] += xv * swk[base + ci * 4 + co];
          av[co] += xv * swv[base + ci * 4 + co];
        }
      }
    }
  }
  float mk = (ak[0]*ak[0] + ak[1]*ak[1] + ak[2]*ak[2] + ak[3]*ak[3]) * 0.25f + 1e-6f;
  float mv = (av[0]*av[0] + av[1]*av[1] + av[2]*av[2] + av[3]*av[3]) * 0.25f + 1e-6f;
  float ik = 1.f / sqrtf(mk), iv = 1.f / sqrtf(mv);
  float4 ok = { ak[0]*ik*sb[8],  ak[1]*ik*sb[9],  ak[2]*ik*sb[10], ak[3]*ik*sb[11] };
  float4 ov = { av[0]*iv*sb[12], av[1]*iv*sb[13], av[2]*iv*sb[14], av[3]*iv*sb[15] };
  *(float4*)&nk[(size_t)idx * 4] = ok;
  *(float4*)&nv[(size_t)idx * 4] = ov;
}

// ---------------- mm_nn: A[64,K]@B tile -> slice (R7 + swizzle) ----------------
__device__ __forceinline__ void mm_nn_slice(
    const float* __restrict__ A, int lda, const float* __restrict__ B, int ldb,
    float* __restrict__ Cp, int ldc, int n_t, int k_t, float* smem) {
  float* As = smem;
  float* Bs = smem + 4096;
  int tid = threadIdx.x;
  int n0 = n_t * 64, k0 = k_t * 64;
  {
    int m  = tid >> 2;
    int kb = (tid & 3) * 16;
    const float* Ap = A + (size_t)m * lda + k0 + kb;
    #pragma unroll
    for (int q = 0; q < 4; ++q) {
      float4 v = *(const float4*)(Ap + q * 4);
      As[SWZ(kb + q*4 + 0, m)] = v.x;
      As[SWZ(kb + q*4 + 1, m)] = v.y;
      As[SWZ(kb + q*4 + 2, m)] = v.z;
      As[SWZ(kb + q*4 + 3, m)] = v.w;
    }
    int kr = tid >> 4;
    int nn = (tid & 15) * 4;
    #pragma unroll
    for (int q = 0; q < 4; ++q)
      *(float4*)&Bs[(kr + q*16)*64 + nn] = *(const float4*)(B + (size_t)(k0 + kr + q*16) * ldb + n0 + nn);
  }
  __syncthreads();
  int tx = tid & 15, ty = tid >> 4;
  float acc[4][4] = {{0.f}};
  #pragma unroll 16
  for (int kk = 0; kk < 64; ++kk) {
    float4 a = *(const float4*)&As[kk*64 + ((ty*4) ^ (kk & 16))];
    float4 b = *(const float4*)&Bs[kk*64 + tx * 4];
    MICRO_4x4
  }
  float* Cb = Cp + (size_t)k_t * 64 * ldc + n0 + tx * 4;
  #pragma unroll
  for (int r = 0; r < 4; ++r) {
    float4 v = { acc[r][0], acc[r][1], acc[r][2], acc[r][3] };
    *(float4*)&Cb[(size_t)(ty * 4 + r) * ldc] = v;
  }
}

// ---------------- mm_nt: A[64,K]@B^T (R7 + swizzle both sides) ----------------
__device__ __forceinline__ void mm_nt_slice(
    const float* __restrict__ A, int lda, const float* __restrict__ B, int ldb,
    float* __restrict__ Cp, int ldc, int n_t, int k_t, float* smem) {
  float* As = smem;
  float* Bs = smem + 4096;
  int tid = threadIdx.x;
  int n0 = n_t * 64, k0 = k_t * 64;
  {
    int m  = tid >> 2;
    int kb = (tid & 3) * 16;
    const float* Ap = A + (size_t)m * lda + k0 + kb;
    const float* Bp = B + (size_t)(n0 + m) * ldb + k0 + kb;
    #pragma unroll
    for (int q = 0; q < 4; ++q) {
      float4 va = *(const float4*)(Ap + q * 4);
      As[SWZ(kb + q*4 + 0, m)] = va.x;
      As[SWZ(kb + q*4 + 1, m)] = va.y;
      As[SWZ(kb + q*4 + 2, m)] = va.z;
      As[SWZ(kb + q*4 + 3, m)] = va.w;
      float4 vb = *(const float4*)(Bp + q * 4);
      Bs[SWZ(kb + q*4 + 0, m)] = vb.x;
      Bs[SWZ(kb + q*4 + 1, m)] = vb.y;
      Bs[SWZ(kb + q*4 + 2, m)] = vb.z;
      Bs[SWZ(kb + q*4 + 3, m)] = vb.w;
    }
  }
  __syncthreads();
  int tx = tid & 15, ty = tid >> 4;
  float acc[4][4] = {{0.f}};
  #pragma unroll 16
  for (int kk = 0; kk < 64; ++kk) {
    float4 a = *(const float4*)&As[kk*64 + ((ty*4) ^ (kk & 16))];
    float4 b = *(const float4*)&Bs[kk*64 + ((tx*4) ^ (kk & 16))];
    MICRO_4x4
  }
  float* Cb = Cp + (size_t)k_t * 64 * ldc + n0 + tx * 4;
  #pragma unroll
  for (int r = 0; r < 4; ++r) {
    float4 v = { acc[r][0], acc[r][1], acc[r][2], acc[r][3] };
    *(float4*)&Cb[(size_t)(ty * 4 + r) * ldc] = v;
  }
}

// ---------------- upd64: Cnew = Cold - A^T B (proven R3/R7; float4 staging, no conflict) ----------------
__device__ __forceinline__ void upd64_dev(
    const float* __restrict__ A, int P,
    const float* __restrict__ B, int Q,
    const float* __restrict__ Cold, float* __restrict__ Cnew,
    int bx, int by, float* smem) {
  float* As = smem;
  float* Bs = smem + 4096;
  int tid = threadIdx.x;
  int q0 = bx * 64;
  int p0 = by * 64;
  {
    int i = tid >> 4;
    int c = (tid & 15) * 4;
    #pragma unroll
    for (int q = 0; q < 4; ++q) {
      *(float4*)&As[(i + q*16)*64 + c] = *(const float4*)(A + (size_t)(i + q*16) * P + p0 + c);
      *(float4*)&Bs[(i + q*16)*64 + c] = *(const float4*)(B + (size_t)(i + q*16) * Q + q0 + c);
    }
  }
  __syncthreads();
  int tx = tid & 15, ty = tid >> 4;
  float acc[4][4] = {{0.f}};
  #pragma unroll 16
  for (int i = 0; i < 64; ++i) {
    float4 a = *(const float4*)&As[i*64 + ty * 4];
    float4 b = *(const float4*)&Bs[i*64 + tx * 4];
    MICRO_4x4
  }
  #pragma unroll
  for (int r = 0; r < 4; ++r) {
    size_t off = (size_t)(p0 + ty*4 + r) * Q + q0 + tx*4;
    float4 co = *(const float4*)&Cold[off];
    float4 v = { co.x - acc[r][0], co.y - acc[r][1], co.z - acc[r][2], co.w - acc[r][3] };
    *(float4*)&Cnew[off] = v;
  }
}

// ---------------- u1: pair-slice jobs with VGPR prefetch + swizzle ----------------
__device__ __forceinline__ void kk_slice2(int p, int s2, const float* __restrict__ nk,
                                          float* __restrict__ KKsl, float* smem) {
  float* As = smem;
  float* Bs = smem + 4096;
  int tid = threadIdx.x;
  int c = 0;
  while ((c + 1) * (c + 2) / 2 <= p) ++c;
  int j = p - c * (c + 1) / 2;
  const float* A = nk + (size_t)c * 64 * DM;
  const float* B = nk + (size_t)j * 64 * DM;
  int m  = tid >> 2;
  int kb = (tid & 3) * 16;
  int tx = tid & 15, ty = tid >> 4;
  float acc[4][4] = {{0.f}};
  int nit = (s2 < 24) ? 2 : 1;        // 49 chunks: 24 pairs + 1 single
  int k00 = s2 * 2 * 64;
  float4 pa[4], pb[4];
  #pragma unroll
  for (int q = 0; q < 4; ++q) {
    pa[q] = *(const float4*)(A + (size_t)m * DM + k00 + kb + q * 4);
    pb[q] = *(const float4*)(B + (size_t)m * DM + k00 + kb + q * 4);
  }
  for (int it = 0; it < nit; ++it) {
    __syncthreads();
    #pragma unroll
    for (int q = 0; q < 4; ++q) {
      As[SWZ(kb + q*4 + 0, m)] = pa[q].x;
      As[SWZ(kb + q*4 + 1, m)] = pa[q].y;
      As[SWZ(kb + q*4 + 2, m)] = pa[q].z;
      As[SWZ(kb + q*4 + 3, m)] = pa[q].w;
      Bs[SWZ(kb + q*4 + 0, m)] = pb[q].x;
      Bs[SWZ(kb + q*4 + 1, m)] = pb[q].y;
      Bs[SWZ(kb + q*4 + 2, m)] = pb[q].z;
      Bs[SWZ(kb + q*4 + 3, m)] = pb[q].w;
    }
    __syncthreads();
    if (it + 1 < nit) {
      int k0n = k00 + 64;
      #pragma unroll
      for (int q = 0; q < 4; ++q) {
        pa[q] = *(const float4*)(A + (size_t)m * DM + k0n + kb + q * 4);
        pb[q] = *(const float4*)(B + (size_t)m * DM + k0n + kb + q * 4);
      }
    }
    #pragma unroll 16
    for (int kk = 0; kk < 64; ++kk) {
      float4 a = *(const float4*)&As[kk*64 + ((ty*4) ^ (kk & 16))];
      float4 b = *(const float4*)&Bs[kk*64 + ((tx*4) ^ (kk & 16))];
      MICRO_4x4
    }
  }
  float* dst = KKsl + ((size_t)p * 25 + s2) * 4096;
  #pragma unroll
  for (int r = 0; r < 4; ++r) {
    float4 v = { acc[r][0], acc[r][1], acc[r][2], acc[r][3] };
    *(float4*)&dst[(ty*4 + r) * 64 + tx*4] = v;
  }
}

__device__ __forceinline__ void hb_slice2(int jb, const float* __restrict__ nkA,
                                          const float* __restrict__ W1,
                                          float* __restrict__ Hb_sl, float* smem) {
  float* As = smem;
  float* Bs = smem + 4096;
  int tid = threadIdx.x;
  int s2 = jb % 25;
  int nt = (jb / 25) % 8;
  int mt = jb / 200;
  int n0 = nt * 64;
  int m0 = mt * 64;
  int m  = tid >> 2;
  int kb = (tid & 3) * 16;
  int kr = tid >> 4;
  int nn = (tid & 15) * 4;
  int tx = tid & 15, ty = tid >> 4;
  float acc[4][4] = {{0.f}};
  int nit = (s2 < 24) ? 2 : 1;
  int k00 = s2 * 2 * 64;
  float4 pa[4], pb[4];
  #pragma unroll
  for (int q = 0; q < 4; ++q) {
    pa[q] = *(const float4*)(nkA + (size_t)(m0 + m) * DM + k00 + kb + q * 4);
    pb[q] = *(const float4*)(W1 + (size_t)(k00 + kr + q*16) * DH + n0 + nn);
  }
  for (int it = 0; it < nit; ++it) {
    __syncthreads();
    #pragma unroll
    for (int q = 0; q < 4; ++q) {
      As[SWZ(kb + q*4 + 0, m)] = pa[q].x;
      As[SWZ(kb + q*4 + 1, m)] = pa[q].y;
      As[SWZ(kb + q*4 + 2, m)] = pa[q].z;
      As[SWZ(kb + q*4 + 3, m)] = pa[q].w;
      *(float4*)&Bs[(kr + q*16)*64 + nn] = pb[q];
    }
    __syncthreads();
    if (it + 1 < nit) {
      int k0n = k00 + 64;
      #pragma unroll
      for (int q = 0; q < 4; ++q) {
        pa[q] = *(const float4*)(nkA + (size_t)(m0 + m) * DM + k0n + kb + q * 4);
        pb[q] = *(const float4*)(W1 + (size_t)(k0n + kr + q*16) * DH + n0 + nn);
      }
    }
    #pragma unroll 16
    for (int kk = 0; kk < 64; ++kk) {
      float4 a = *(const float4*)&As[kk*64 + ((ty*4) ^ (kk & 16))];
      float4 b = *(const float4*)&Bs[kk*64 + tx * 4];
      MICRO_4x4
    }
  }
  float* dst = Hb_sl + (size_t)s2 * 262144;
  #pragma unroll
  for (int r = 0; r < 4; ++r) {
    float4 v = { acc[r][0], acc[r][1], acc[r][2], acc[r][3] };
    *(float4*)&dst[(size_t)(m0 + ty*4 + r) * 512 + n0 + tx*4] = v;
  }
}

__global__ __launch_bounds__(256) void u1_kernel(
    const float* __restrict__ nk, const float* __restrict__ W1,
    float* __restrict__ KKsl, float* __restrict__ Hb_sl) {
  __shared__ float smem[8192];
  int job = blockIdx.x;
  if (job < 900) kk_slice2(job / 25, job % 25, nk, KKsl, smem);
  else           hb_slice2(job - 900, nk, W1, Hb_sl, smem);
}

// u2: KKf (sum 25) + Hbase (sum 25) + fused hred for chunk 0 (j<32768)
__global__ __launch_bounds__(256) void u2_kernel(
    const float* __restrict__ KKsl, const float* __restrict__ Hb_sl,
    float* __restrict__ KKf, float* __restrict__ Hbase,
    const float* __restrict__ b1,
    float* __restrict__ Hh, float* __restrict__ G, float* __restrict__ Gp) {
  int i = blockIdx.x * 256 + threadIdx.x;
  if (i < 147456) {
    int pair = i >> 12, e = i & 4095;
    float s = 0.f;
    #pragma unroll
    for (int t = 0; t < 25; ++t) s += KKsl[((size_t)pair * 25 + t) * 4096 + e];
    KKf[i] = s;
  } else {
    int j = i - 147456;   // < 262144
    float s = 0.f;
    #pragma unroll
    for (int t = 0; t < 25; ++t) s += Hb_sl[(size_t)t * 262144 + j];
    Hbase[j] = s;
    if (j < 32768) {      // chunk 0 rows: emit H/G/Gp directly
      Hh[j] = s;
      float g, gp;
      gelu_both(s + b1[j & 511], g, gp);
      G[j] = g; Gp[j] = gp;
    }
  }
}

// ---------------- hred ----------------
__device__ __forceinline__ void hred_body(
    int j, const float* __restrict__ Hb_c, const float* __restrict__ Hcorr, int nsl,
    const float* __restrict__ b1v,
    float* __restrict__ H, float* __restrict__ G, float* __restrict__ Gp) {
  float s = Hb_c[j];
  for (int t = 0; t < nsl; ++t) s -= Hcorr[(size_t)t * 32768 + j];
  H[j] = s;
  float g, gp;
  gelu_both(s + b1v[j & 511], g, gp);
  G[j] = g; Gp[j] = gp;
}

// ---------------- hs_corr / gelu2k jobs (R7 + swizzle on KK side) ----------------
__device__ __forceinline__ void hs_corr_job(
    const float* __restrict__ KK, const float* __restrict__ Ewj,
    float* __restrict__ dst, int bx, float* smem) {
  float* As = smem;
  float* Bs = smem + 4096;
  int tid = threadIdx.x;
  int n0 = bx * 64;
  {
    int m = tid >> 2, ib = (tid & 3) * 16;
    #pragma unroll
    for (int q = 0; q < 4; ++q) {
      float4 v = *(const float4*)(KK + m * 64 + ib + q * 4);
      As[SWZ(ib + q*4 + 0, m)] = v.x;
      As[SWZ(ib + q*4 + 1, m)] = v.y;
      As[SWZ(ib + q*4 + 2, m)] = v.z;
      As[SWZ(ib + q*4 + 3, m)] = v.w;
    }
    int kr = tid >> 4, nn = (tid & 15) * 4;
    #pragma unroll
    for (int q = 0; q < 4; ++q)
      *(float4*)&Bs[(kr + q*16)*64 + nn] = *(const float4*)(Ewj + (size_t)(kr + q*16) * DH + n0 + nn);
  }
  __syncthreads();
  int tx = tid & 15, ty = tid >> 4;
  float acc[4][4] = {{0.f}};
  #pragma unroll 16
  for (int kk = 0; kk < 64; ++kk) {
    float4 a = *(const float4*)&As[kk*64 + ((ty*4) ^ (kk & 16))];
    float4 b = *(const float4*)&Bs[kk*64 + tx * 4];
    MICRO_4x4
  }
  #pragma unroll
  for (int r = 0; r < 4; ++r) {
    float4 v = { acc[r][0], acc[r][1], acc[r][2], acc[r][3] };
    *(float4*)&dst[(ty*4 + r) * DH + n0 + tx*4] = v;
  }
}

__device__ __forceinline__ void gelu2k_job(
    const float* __restrict__ KKcc, const float* __restrict__ Ew,
    const float* __restrict__ H, const float* __restrict__ b1n,
    float* __restrict__ G2, int n0, float* smem) {
  float* KKs = smem;
  float* Ews = smem + 4096;
  int tid = threadIdx.x;
  #pragma unroll
  for (int q = 0; q < 4; ++q) {
    int e4 = q * 256 + tid;
    *(float4*)&KKs[e4 * 4] = *(const float4*)(KKcc + e4 * 4);
  }
  {
    int i = tid >> 2, c4 = (tid & 3) * 4;
    *(float4*)&Ews[i * 16 + c4] = *(const float4*)(Ew + (size_t)i * DH + n0 + c4);
  }
  __syncthreads();
  #pragma unroll
  for (int q = 0; q < 4; ++q) {
    int e = q * 256 + tid;
    int mrow = e >> 4, cc = e & 15;
    float corr = 0.f;
    #pragma unroll 16
    for (int i = 0; i < 64; ++i) corr += KKs[mrow * 64 + i] * Ews[i * 16 + cc];
    float xx = H[mrow * DH + n0 + cc] - corr + b1n[n0 + cc];
    G2[mrow * DH + n0 + cc] = gelu_only(xx);
  }
}

// ================= per-chunk pipeline kernels =================
// P3 for chunk 0 (upfront)
__global__ __launch_bounds__(256) void p3_kernel(
    const float* __restrict__ G, const float* __restrict__ W2c,
    float* __restrict__ Spred) {
  __shared__ float smem[8192];
  mm_nn_slice(G, DH, W2c, DM, Spred, DM, blockIdx.x % 49, blockIdx.x / 49, smem);
}

// kA: Dw + partial colsums (49 n-tiles x 8 row-groups = 392 blocks)
__global__ __launch_bounds__(256) void red_Db2(
    const float* __restrict__ Dp, const float* __restrict__ b2c,
    const float* __restrict__ V, float wc2,
    float* __restrict__ Dw, float* __restrict__ Dcs) {
  __shared__ float sm[256];
  int tid = threadIdx.x;
  int nt = blockIdx.x % 49, rg = blockIdx.x / 49;
  int col = nt * 64 + (tid & 63);
  int r0 = rg * 8 + (tid >> 6) * 2;
  float bb = b2c[col];
  float cs = 0.f;
  #pragma unroll
  for (int rr = 0; rr < 2; ++rr) {
    size_t off = (size_t)(r0 + rr) * DM + col;
    float s = 0.f;
    #pragma unroll
    for (int t = 0; t < 8; ++t) s += Dp[(size_t)t * 200704 + off];
    float d = wc2 * (s + bb - V[off]);
    Dw[off] = d;
    cs += d;
  }
  sm[tid] = cs;
  __syncthreads();
  if (tid < 128) sm[tid] += sm[tid + 128];
  __syncthreads();
  if (tid < 64) Dcs[(size_t)rg * DM + col] = sm[tid] + sm[tid + 64];
}

// kB: P4 E-slices (392) || W2n = W2c - G^T Dw (392)
__global__ __launch_bounds__(256) void p4w2_kernel(
    const float* __restrict__ Dw, const float* __restrict__ W2c,
    const float* __restrict__ G, float* __restrict__ SpE,
    float* __restrict__ W2n) {
  __shared__ float smem[8192];
  int b = blockIdx.x;
  if (b < 392) mm_nt_slice(Dw, DM, W2c, DM, SpE, DH, b & 7, b >> 3, smem);
  else {
    int li = b - 392;
    upd64_dev(G, DH, Dw, DM, W2c, W2n, li % 49, li / 49, smem);
  }
}

// kC: Ew + b1 update (128) || b2 finalize from Dcs (49)
__global__ __launch_bounds__(256) void ewb1_kernel(
    const float* __restrict__ Esl, const float* __restrict__ Gp,
    float* __restrict__ Ew, const float* __restrict__ b1old, float* __restrict__ b1new,
    const float* __restrict__ Dcs, const float* __restrict__ b2c,
    float* __restrict__ b2n) {
  __shared__ float smem[256];
  int tid = threadIdx.x;
  int b = blockIdx.x;
  if (b < 128) {
    int n0 = b * 4;
    int row = tid >> 2, c = tid & 3;
    int col = n0 + c;
    float s = 0.f;
    #pragma unroll
    for (int sl = 0; sl < 49; ++sl) s += Esl[(size_t)sl * 32768 + row * 512 + col];
    float ew = s * Gp[row * 512 + col];
    Ew[row * 512 + col] = ew;
    smem[tid] = ew;
    __syncthreads();
    for (int off = 128; off >= 4; off >>= 1) {
      if (tid < off) smem[tid] += smem[tid + off];
      __syncthreads();
    }
    if (tid < 4) b1new[n0 + tid] = b1old[n0 + tid] - smem[tid];
  } else {
    int jb = b - 128;                 // < 49
    if (tid < 64) {
      int col = jb * 64 + tid;
      float s = 0.f;
      #pragma unroll
      for (int rg = 0; rg < 8; ++rg) s += Dcs[(size_t)rg * DM + col];
      b2n[col] = b2c[col] - s;
    }
  }
}

// kD: G2 (32) || Hcorr j=ch for chunk ch+1 (8, if ch<7)
__global__ __launch_bounds__(256) void g2s_kernel(
    const float* __restrict__ KKf, int tri, int ch,
    const float* __restrict__ Ewst, const float* __restrict__ H,
    const float* __restrict__ b1n,
    float* __restrict__ G2, float* __restrict__ Hcorr) {
  __shared__ float smem[8192];
  int b = blockIdx.x;
  if (b < 32) {
    gelu2k_job(KKf + (size_t)(tri + ch) * 4096, Ewst + (size_t)ch * 32768,
               H, b1n, G2, b * 16, smem);
  } else {
    int bx = b - 32;
    int trin = (ch + 1) * (ch + 2) / 2;
    hs_corr_job(KKf + (size_t)(trin + ch) * 4096, Ewst + (size_t)ch * 32768,
                Hcorr + (size_t)ch * 32768, bx, smem);
  }
}

// kE: P7 Y-slices (392) || hred for chunk ch+1 (128, if ch<7)
__global__ __launch_bounds__(256) void p7h_kernel(
    const float* __restrict__ G2, const float* __restrict__ W2n,
    float* __restrict__ SpY,
    const float* __restrict__ Hbase_n, const float* __restrict__ Hcorr, int nsl,
    const float* __restrict__ b1n,
    float* __restrict__ H, float* __restrict__ Gnext, float* __restrict__ Gp) {
  __shared__ float smem[8192];
  int b = blockIdx.x;
  if (b < 392) {
    mm_nn_slice(G2, DH, W2n, DM, SpY, DM, b % 49, b / 49, smem);
  } else {
    int j = (b - 392) * 256 + threadIdx.x;   // < 32768
    hred_body(j, Hbase_n, Hcorr, nsl, b1n, H, Gnext, Gp);
  }
}

// kF: out rows (784) || P3 for chunk ch+1 (392, if ch<7)
//     || Hcorr slices for chunk ch+2, j<ch+1 (8*(ch+1), if ch<6)
__global__ __launch_bounds__(256) void redyp3_kernel(
    const float* __restrict__ SpY, const float* __restrict__ b2n,
    float* __restrict__ out, int t0,
    const float* __restrict__ Gnext, const float* __restrict__ W2n,
    float* __restrict__ Spred,
    const float* __restrict__ KKf, int ch,
    const float* __restrict__ Ewst, float* __restrict__ Hcorr) {
  __shared__ float smem[8192];
  int b = blockIdx.x;
  int tid = threadIdx.x;
  if (b < 784) {
    int j = b * 256 + tid;
    float s = 0.f;
    #pragma unroll
    for (int t = 0; t < 8; ++t) s += SpY[(size_t)t * 200704 + j];
    int i = j / DM;
    int d = j - i * DM;
    out[(size_t)t0 * DM + j] = s + b2n[d];
  } else if (b < 1176) {
    int b2 = b - 784;
    mm_nn_slice(Gnext, DH, W2n, DM, Spred, DM, b2 % 49, b2 / 49, smem);
  } else {
    int j2 = b - 1176;                 // < 8*(ch+1)
    int j = j2 >> 3, bx = j2 & 7;      // j <= ch
    int cn2 = ch + 2;
    int trin = cn2 * (cn2 + 1) / 2;
    hs_corr_job(KKf + (size_t)(trin + j) * 4096, Ewst + (size_t)j * 32768,
                Hcorr + (size_t)j * 32768, bx, smem);
  }
}

extern "C" void kernel_launch(void* const* d_in, const int* in_sizes, int n_in,
                              void* d_out, int out_size, void* d_ws, size_t ws_size,
                              hipStream_t stream) {
  const float* x  = (const float*)d_in[0];
  const float* wk = (const float*)d_in[1];
  const float* bk = (const float*)d_in[2];
  const float* wv = (const float*)d_in[3];
  const float* bv = (const float*)d_in[4];
  const float* sk = (const float*)d_in[5];
  const float* sv = (const float*)d_in[6];
  const float* W1 = (const float*)d_in[7];
  const float* b1 = (const float*)d_in[8];
  const float* W2 = (const float*)d_in[9];
  const float* b2 = (const float*)d_in[10];
  float* out = (float*)d_out;
  float* ws  = (float*)d_ws;

  // workspace layout (floats)
  float* nk    = ws;                       // 1,605,632
  float* nv    = nk + 1605632;             // 1,605,632
  float* W2A   = nv + 1605632;             // 1,605,632
  float* W2B   = W2A + 1605632;            // 1,605,632
  float* Spred = W2B + 1605632;            // 1,605,632
  float* SpY   = Spred + 1605632;          // 1,605,632
  float* Hb_sl = SpY + 1605632;            // 6,553,600 (25 x 262144)
  float* KKsl  = Hb_sl + 6553600;          // 3,686,400 (36 x 25 x 4096)
  float* Hbase = KKsl + 3686400;           // 262,144
  float* KKf   = Hbase + 262144;           // 147,456
  float* Hh    = KKf + 147456;             // 32,768
  float* GA    = Hh + 32768;               // 32,768
  float* GB    = GA + 32768;               // 32,768
  float* Gp    = GB + 32768;               // 32,768
  float* Dw    = Gp + 32768;               // 200,704
  float* Dcs   = Dw + 200704;              // 25,088 (8 x 3136)
  float* Ewst  = Dcs + 25088;              // 262,144 (8 x 32768)
  float* Hcorr = Ewst + 262144;            // 229,376 (7 x 32768)
  float* b1ws  = Hcorr + 229376;           // 512
  float* b2ws  = b1ws + 512;               // 3,136
  float* W2buf[2] = { W2A, W2B };
  float* Gbuf[2]  = { GA, GB };

  // weights[i] = ETA0 * ALPHA^i * (ALPHA^63 / ALPHA^i) = ETA0 * ALPHA^63 (constant)
  float wc2 = 2.0f * (float)(0.1 * pow(0.9, 63.0));

  conv_rms<<<1568, 256, 0, stream>>>(x, wk, bk, wv, bv, sk, sv, nk, nv);
  u1_kernel<<<2500, 256, 0, stream>>>(nk, W1, KKsl, Hb_sl);
  u2_kernel<<<1600, 256, 0, stream>>>(KKsl, Hb_sl, KKf, Hbase, b1, Hh, Gbuf[0], Gp);
  p3_kernel<<<392, 256, 0, stream>>>(Gbuf[0], W2, Spred);

  for (int ch = 0; ch < 8; ++ch) {
    const float* V   = nv + (size_t)ch * 200704;
    const float* b1c = ch ? b1ws : b1;
    const float* b2c = ch ? b2ws : b2;
    const float* W2c = ch ? W2buf[(ch - 1) & 1] : W2;
    float* W2n  = W2buf[ch & 1];
    float* Gcur = Gbuf[ch & 1];
    float* Gnxt = Gbuf[(ch + 1) & 1];
    float* Ewc  = Ewst + (size_t)ch * 32768;
    int tri = ch * (ch + 1) / 2;

    // kA: Dw + partial colsums
    red_Db2<<<392, 256, 0, stream>>>(Spred, b2c, V, wc2, Dw, Dcs);
    // kB: E slices (into Spred) || W2n = W2c - G^T Dw
    p4w2_kernel<<<784, 256, 0, stream>>>(Dw, W2c, Gcur, Spred, W2n);
    // kC: Ew + b1 update || b2 finalize
    ewb1_kernel<<<177, 256, 0, stream>>>(Spred, Gp, Ewc, b1c, b1ws, Dcs, b2c, b2ws);
    // kD: G2 (overwrites Gcur) || Hcorr j=ch for chunk ch+1
    g2s_kernel<<<32 + (ch < 7 ? 8 : 0), 256, 0, stream>>>(
        KKf, tri, ch, Ewst, Hh, b1ws, Gcur, Hcorr);
    // kE: P7 Y-slices || hred for chunk ch+1
    p7h_kernel<<<392 + (ch < 7 ? 128 : 0), 256, 0, stream>>>(
        Gcur, W2n, SpY,
        Hbase + (size_t)(ch + 1) * 32768, Hcorr, ch + 1, b1ws, Hh, Gnxt, Gp);
    // kF: out rows || P3 for chunk ch+1 || Hcorr for chunk ch+2 (j<=ch)
    int gF = 784 + (ch < 7 ? 392 + (ch < 6 ? 8 * (ch + 1) : 0) : 0);
    redyp3_kernel<<<gF, 256, 0, stream>>>(
        SpY, b2ws, out, ch * 64, Gnxt, W2n, Spred, KKf, ch, Ewst, Hcorr);
  }
}